// Round 1
// baseline (220.411 us; speedup 1.0000x reference)
//
#include <hip/hip_runtime.h>

typedef __attribute__((ext_vector_type(4))) int i32x4;

// ---------------------------------------------------------------------------
// Helpers
// ---------------------------------------------------------------------------
__device__ __forceinline__ void gload_lds16(const void* g, void* l) {
  // async global->LDS, 16B per lane. LDS dest must be wave-uniform base + lane*16.
  __builtin_amdgcn_global_load_lds((const __attribute__((address_space(1))) void*)g,
                                   (__attribute__((address_space(3))) void*)l,
                                   16, 0, 0);
}

// chunk swizzle: rows are 64B = 4 chunks of 16B. XOR chunk with swz(row) so that
// the 16-lane fragment read (same chunk, rows r..r+15) spreads over all 8
// 16B bank-groups (2-way residual aliasing = free).
__device__ __forceinline__ int swz4(int r) { return (r ^ (r >> 2)) & 3; }

// ---------------------------------------------------------------------------
// Quantize f32 -> int8 (round-half-even like jnp.round, clamp to +-127)
// ---------------------------------------------------------------------------
__global__ void quant_i8_kernel(const float* __restrict__ in,
                                signed char* __restrict__ out,
                                const float* __restrict__ amax, int n4) {
  const float s = 127.0f / amax[0];
  int i = blockIdx.x * blockDim.x + threadIdx.x;
  const int stride = gridDim.x * blockDim.x;
  const float4* __restrict__ in4 = (const float4*)in;
  int* __restrict__ o4 = (int*)out;
  for (; i < n4; i += stride) {
    float4 v = in4[i];
    int q0 = (int)rintf(fminf(fmaxf(v.x * s, -127.0f), 127.0f));
    int q1 = (int)rintf(fminf(fmaxf(v.y * s, -127.0f), 127.0f));
    int q2 = (int)rintf(fminf(fmaxf(v.z * s, -127.0f), 127.0f));
    int q3 = (int)rintf(fminf(fmaxf(v.w * s, -127.0f), 127.0f));
    o4[i] = (q0 & 255) | ((q1 & 255) << 8) | ((q2 & 255) << 16) | ((q3 & 255) << 24);
  }
}

// ---------------------------------------------------------------------------
// Int8 GEMM: out[N,M] = dequant(qx[N,K] . qw[M,K]^T) + bias
// 128x128 tile, BK=64, 4 waves (each 64x64 = 4x4 fragments of 16x16),
// mfma_i32_16x16x64_i8, global_load_lds width-16 staging, chunk-swizzled LDS.
// ---------------------------------------------------------------------------
__global__ __launch_bounds__(256, 2) void gemm_i8_kernel(
    const signed char* __restrict__ qx,   // [N,K]
    const signed char* __restrict__ qw,   // [M,K]
    const float* __restrict__ bias,       // [M]
    const float* __restrict__ amax_x,
    const float* __restrict__ amax_w,
    float* __restrict__ out,              // [N,M]
    int N, int M, int K) {
  constexpr int BM = 128;   // N-dim tile
  constexpr int BN = 128;   // M-dim tile
  constexpr int BK = 64;    // K per iteration (one MFMA K-step)

  __shared__ alignas(16) signed char As[BM * BK];  // rows of qx, 64B rows
  __shared__ alignas(16) signed char Bs[BN * BK];  // rows of qw

  const int tid  = threadIdx.x;
  const int wid  = tid >> 6;
  const int lane = tid & 63;
  const int l15  = lane & 15;   // fragment row selector
  const int l4   = lane >> 4;   // k-chunk selector (0..3)

  const int rowBase = blockIdx.y * BM;  // N
  const int colBase = blockIdx.x * BN;  // M

  const int wRow = (wid >> 1) * 64;  // wave's sub-tile within block (N)
  const int wCol = (wid & 1) * 64;   // (M)

  // staging coords: thread t handles (row tr, chunk-position tp); 2 issues
  // cover 128 rows per operand. LDS dest is linear (tid*16);
  // global source chunk is inverse-swizzled so swizzled reads see logical data.
  const int tr = tid >> 2;
  const int tp = tid & 3;
  const int ra = tr, rb = tr + 64;
  const int ca0 = (tp ^ swz4(ra)) * 16;
  const int ca1 = (tp ^ swz4(rb)) * 16;

  const signed char* srcA0 = qx + (size_t)(rowBase + ra) * K + ca0;
  const signed char* srcA1 = qx + (size_t)(rowBase + rb) * K + ca1;
  const signed char* srcB0 = qw + (size_t)(colBase + ra) * K + ca0;
  const signed char* srcB1 = qw + (size_t)(colBase + rb) * K + ca1;

  i32x4 acc[4][4] = {};

  // precompute swizzled LDS read offsets (row, chunk l4)
  int offA[4], offB[4];
#pragma unroll
  for (int i = 0; i < 4; ++i) {
    int r = wRow + i * 16 + l15;
    offA[i] = r * 64 + (l4 ^ swz4(r)) * 16;
    int c = wCol + i * 16 + l15;
    offB[i] = c * 64 + (l4 ^ swz4(c)) * 16;
  }

  for (int kt = 0; kt < K; kt += BK) {
    gload_lds16(srcA0 + kt, As + tid * 16);
    gload_lds16(srcA1 + kt, As + 4096 + tid * 16);
    gload_lds16(srcB0 + kt, Bs + tid * 16);
    gload_lds16(srcB1 + kt, Bs + 4096 + tid * 16);
    __syncthreads();  // waits vmcnt(0) then barrier

    i32x4 a[4], b[4];
#pragma unroll
    for (int i = 0; i < 4; ++i) a[i] = *(const i32x4*)(As + offA[i]);
#pragma unroll
    for (int j = 0; j < 4; ++j) b[j] = *(const i32x4*)(Bs + offB[j]);

#pragma unroll
    for (int i = 0; i < 4; ++i)
#pragma unroll
      for (int j = 0; j < 4; ++j)
        acc[i][j] = __builtin_amdgcn_mfma_i32_16x16x64_i8(a[i], b[j], acc[i][j], 0, 0, 0);

    __syncthreads();  // protect LDS overwrite next iteration
  }

  // epilogue: dequant + bias. C/D layout: col = lane&15, row = (lane>>4)*4 + reg
  const float dq = amax_x[0] * amax_w[0] * (1.0f / (127.0f * 127.0f));
#pragma unroll
  for (int j = 0; j < 4; ++j) {
    const int col = colBase + wCol + j * 16 + l15;
    const float bv = bias[col];
#pragma unroll
    for (int i = 0; i < 4; ++i) {
      const int row = rowBase + wRow + i * 16 + l4 * 4;
#pragma unroll
      for (int r = 0; r < 4; ++r) {
        out[(size_t)(row + r) * M + col] = (float)acc[i][j][r] * dq + bv;
      }
    }
  }
}

// ---------------------------------------------------------------------------
// Launch
// ---------------------------------------------------------------------------
extern "C" void kernel_launch(void* const* d_in, const int* in_sizes, int n_in,
                              void* d_out, int out_size, void* d_ws, size_t ws_size,
                              hipStream_t stream) {
  const float* x      = (const float*)d_in[0];
  const float* w      = (const float*)d_in[1];
  const float* bias   = (const float*)d_in[2];
  const float* amax_x = (const float*)d_in[3];
  const float* amax_w = (const float*)d_in[4];
  float* out = (float*)d_out;

  const int M = in_sizes[2];                 // 4096
  const int K = in_sizes[1] / M;             // 4096
  const int N = (int)((long)in_sizes[0] / K);  // 8192

  signed char* qx = (signed char*)d_ws;              // [N,K] int8
  signed char* qw = qx + (size_t)N * K;              // [M,K] int8

  quant_i8_kernel<<<2048, 256, 0, stream>>>(x, qx, amax_x, N * (K / 4));
  quant_i8_kernel<<<2048, 256, 0, stream>>>(w, qw, amax_w, M * (K / 4));

  dim3 grid(M / 128, N / 128);
  gemm_i8_kernel<<<grid, 256, 0, stream>>>(qx, qw, bias, amax_x, amax_w, out,
                                           N, M, K);
}

// Round 3
// 191.841 us; speedup vs baseline: 1.1489x; 1.1489x over previous
//
#include <hip/hip_runtime.h>

typedef __attribute__((ext_vector_type(4))) int i32x4;

// ---------------------------------------------------------------------------
// Helpers
// ---------------------------------------------------------------------------
__device__ __forceinline__ void gload_lds16(const void* g, void* l) {
  // async global->LDS, 16B/lane. LDS dest must be wave-uniform base + lane*16.
  __builtin_amdgcn_global_load_lds((const __attribute__((address_space(1))) void*)g,
                                   (__attribute__((address_space(3))) void*)l,
                                   16, 0, 0);
}

#define BARRIER() __builtin_amdgcn_s_barrier()
#define LGKM0()   asm volatile("s_waitcnt lgkmcnt(0)" ::: "memory")
#define VMCNT4()  asm volatile("s_waitcnt vmcnt(4)" ::: "memory")

// ---------------------------------------------------------------------------
// Quantize f32 -> int8 (round-half-even like jnp.round, clamp to +-127)
// ---------------------------------------------------------------------------
__global__ void quant_i8_kernel(const float* __restrict__ in,
                                signed char* __restrict__ out,
                                const float* __restrict__ amax, int n4) {
  const float s = 127.0f / amax[0];
  int i = blockIdx.x * blockDim.x + threadIdx.x;
  const int stride = gridDim.x * blockDim.x;
  const float4* __restrict__ in4 = (const float4*)in;
  int* __restrict__ o4 = (int*)out;
  for (; i < n4; i += stride) {
    float4 v = in4[i];
    int q0 = (int)rintf(fminf(fmaxf(v.x * s, -127.0f), 127.0f));
    int q1 = (int)rintf(fminf(fmaxf(v.y * s, -127.0f), 127.0f));
    int q2 = (int)rintf(fminf(fmaxf(v.z * s, -127.0f), 127.0f));
    int q3 = (int)rintf(fminf(fmaxf(v.w * s, -127.0f), 127.0f));
    o4[i] = (q0 & 255) | ((q1 & 255) << 8) | ((q2 & 255) << 16) | ((q3 & 255) << 24);
  }
}

// ---------------------------------------------------------------------------
// 256x256 8-phase int8 GEMM (T2+T3+T4+T5). Race-fixed gate placement:
// vmcnt(4) BEFORE the trailing barriers of P4/P8 (all waves drain, then
// barrier, then reads) — per-wave vmcnt at the top of P1/P5 was a race.
// out[N,M] = dequant(qx[N,K] . qw[M,K]^T) + bias
// 512 thr = 8 waves (2M x 4N), per-wave 128x64, mfma_i32_16x16x64_i8,
// BK=128 int8 (2 k-subtiles of 64), LDS 2dbuf x (A,B) x [256][128B] = 128 KiB.
// Swizzle: 16B-chunk' = chunk ^ (row&7); applied to global SOURCE on staging
// (LDS dest linear, rule #21) and to the ds_read address.
// ---------------------------------------------------------------------------
__global__ __launch_bounds__(512, 2) void gemm_i8_8p(
    const signed char* __restrict__ qx,   // [N,K]
    const signed char* __restrict__ qw,   // [M,K]
    const float* __restrict__ bias,       // [M]
    const float* __restrict__ amax_x,
    const float* __restrict__ amax_w,
    float* __restrict__ out,              // [N,M]
    int N, int M, int K) {
  constexpr int BKB = 128;  // K bytes per tile

  __shared__ signed char lds[4][256 * 128];  // [A0,B0,A1,B1], 32 KiB each

  const int tid  = threadIdx.x;
  const int lane = tid & 63;
  const int wid  = tid >> 6;
  const int wm   = wid >> 2;   // 0..1
  const int wn   = wid & 3;    // 0..3
  const int l15  = lane & 15;
  const int l4   = lane >> 4;

  // bijective XCD-aware block swizzle (nwg = 512, divisible by 8)
  const int nbn = M >> 8;                      // 16
  const int nwg = (N >> 8) * nbn;              // 512
  const int cpx = nwg >> 3;
  const int swz = (blockIdx.x & 7) * cpx + (blockIdx.x >> 3);
  const int rowBase = (swz / nbn) << 8;
  const int colBase = (swz % nbn) << 8;

  // staging source pointers: thread t covers slots {h*1024 + L*512 + t};
  // logical (row = slot>>3, c = (slot&7) ^ (row&7)); LDS dest stays linear.
  const signed char* sA[2][2];
  const signed char* sB[2][2];
#pragma unroll
  for (int h = 0; h < 2; ++h)
#pragma unroll
    for (int L = 0; L < 2; ++L) {
      const int slot = h * 1024 + L * 512 + tid;
      const int row  = slot >> 3;
      const int c    = (slot & 7) ^ (row & 7);
      sA[h][L] = qx + (size_t)(rowBase + row) * K + c * 16;
      sB[h][L] = qw + (size_t)(colBase + row) * K + c * 16;
    }

  signed char* A0 = lds[0];
  signed char* B0 = lds[1];
  signed char* A1 = lds[2];
  signed char* B1 = lds[3];

#define STAGE(dst, src, h, kt)                                             \
  do {                                                                     \
    gload_lds16(src[h][0] + (kt) * BKB, (dst) + (h)*16384 + tid * 16);     \
    gload_lds16(src[h][1] + (kt) * BKB, (dst) + (h)*16384 + 8192 + tid * 16); \
  } while (0)

  // fragment-read addressing (row&7 == l15&7 since frag bases are mult of 16)
  const int ck0 = ((l4) ^ (l15 & 7)) * 16;       // ks=0 chunk offset
  const int ck1 = ((4 + l4) ^ (l15 & 7)) * 16;   // ks=1
  const int aRow0 = (wm * 128 + l15) * 128;
  const int bRow0 = (wn * 64 + l15) * 128;

  i32x4 acc[8][4] = {{{0}}};
  i32x4 af[4][2];
  i32x4 bf[4][2];

#define RDA(R, mb)                                                          \
  {                                                                         \
    _Pragma("unroll") for (int mi = 0; mi < 4; ++mi) {                      \
      af[mi][0] = *(const i32x4*)((R) + aRow0 + ((mb) + mi) * 2048 + ck0);  \
      af[mi][1] = *(const i32x4*)((R) + aRow0 + ((mb) + mi) * 2048 + ck1);  \
    }                                                                       \
  }
#define RDB(R, nb)                                                          \
  {                                                                         \
    _Pragma("unroll") for (int nj = 0; nj < 2; ++nj) {                      \
      bf[(nb) + nj][0] = *(const i32x4*)((R) + bRow0 + ((nb) + nj) * 2048 + ck0); \
      bf[(nb) + nj][1] = *(const i32x4*)((R) + bRow0 + ((nb) + nj) * 2048 + ck1); \
    }                                                                       \
  }
#define MFMAQ(mb, nb)                                                       \
  {                                                                         \
    _Pragma("unroll") for (int mi = 0; mi < 4; ++mi)                        \
        _Pragma("unroll") for (int nj = 0; nj < 2; ++nj)                    \
            _Pragma("unroll") for (int ks = 0; ks < 2; ++ks)                \
                acc[(mb) + mi][(nb) + nj] = __builtin_amdgcn_mfma_i32_16x16x64_i8( \
                    af[mi][ks], bf[(nb) + nj][ks], acc[(mb) + mi][(nb) + nj], 0, 0, 0); \
  }

  const int T = K / BKB;  // 32 K-tiles

  // prologue: tile0 -> A0/B0 (8 loads), tile1's B -> B1 (4 loads).
  // Gate tile0: every wave drains to <=4 outstanding (A0,B0 done; B1 may
  // float), THEN barrier -> all waves' A0/B0 loads are in LDS.
  STAGE(B0, sB, 0, 0); STAGE(B0, sB, 1, 0);
  STAGE(A0, sA, 0, 0); STAGE(A0, sA, 1, 0);
  STAGE(B1, sB, 0, 1); STAGE(B1, sB, 1, 1);
  VMCNT4();
  BARRIER();

  for (int it = 0; it < T / 2; ++it) {
    const int k1 = 2 * it + 1;
    const int k2 = (2 * it + 2 < T) ? 2 * it + 2 : T - 1;  // clamped (stale, never read)
    const int k3 = (2 * it + 3 < T) ? 2 * it + 3 : T - 1;

    // P1: read A0[M0]+B0[N0] (gated at prev end-P8 / prologue); stage A1h0 <- t+1
    RDA(A0, 0); RDB(B0, 0);
    STAGE(A1, sA, 0, k1);
    BARRIER(); LGKM0();
    __builtin_amdgcn_s_setprio(1); MFMAQ(0, 0); __builtin_amdgcn_s_setprio(0);
    BARRIER();

    // P2: read B0[N1]; stage A1h1 <- t+1
    RDB(B0, 2);
    STAGE(A1, sA, 1, k1);
    BARRIER(); LGKM0();
    __builtin_amdgcn_s_setprio(1); MFMAQ(0, 2); __builtin_amdgcn_s_setprio(0);
    BARRIER();

    // P3: read A0[M1]; stage B0h0 <- t+2 (B0 reads all done by P2's trailing barrier)
    RDA(A0, 4);
    STAGE(B0, sB, 0, k2);
    BARRIER(); LGKM0();
    __builtin_amdgcn_s_setprio(1); MFMAQ(4, 0); __builtin_amdgcn_s_setprio(0);
    BARRIER();

    // P4: stage B0h1 <- t+2. GATE tile t+1 (A1 from P1/P2, B1 from prev P7/P8):
    // vmcnt(4) leaves only P3/P4's B0 loads in flight; barrier publishes.
    STAGE(B0, sB, 1, k2);
    BARRIER(); LGKM0();
    __builtin_amdgcn_s_setprio(1); MFMAQ(4, 2); __builtin_amdgcn_s_setprio(0);
    VMCNT4();
    BARRIER();

    // P5: read A1[M0]+B1[N0] (gated at end-P4); stage A0h0 <- t+2
    RDA(A1, 0); RDB(B1, 0);
    STAGE(A0, sA, 0, k2);
    BARRIER(); LGKM0();
    __builtin_amdgcn_s_setprio(1); MFMAQ(0, 0); __builtin_amdgcn_s_setprio(0);
    BARRIER();

    // P6: read B1[N1]; stage A0h1 <- t+2
    RDB(B1, 2);
    STAGE(A0, sA, 1, k2);
    BARRIER(); LGKM0();
    __builtin_amdgcn_s_setprio(1); MFMAQ(0, 2); __builtin_amdgcn_s_setprio(0);
    BARRIER();

    // P7: read A1[M1]; stage B1h0 <- t+3
    RDA(A1, 4);
    STAGE(B1, sB, 0, k3);
    BARRIER(); LGKM0();
    __builtin_amdgcn_s_setprio(1); MFMAQ(4, 0); __builtin_amdgcn_s_setprio(0);
    BARRIER();

    // P8: stage B1h1 <- t+3. GATE tile t+2's A0/B0 (P3-P6 loads):
    // vmcnt(4) leaves only P7/P8's B1 loads in flight; barrier publishes.
    STAGE(B1, sB, 1, k3);
    BARRIER(); LGKM0();
    __builtin_amdgcn_s_setprio(1); MFMAQ(4, 2); __builtin_amdgcn_s_setprio(0);
    VMCNT4();
    BARRIER();
  }

  // epilogue: dequant + bias. C/D: col = lane&15, row = (lane>>4)*4 + reg
  const float dq = amax_x[0] * amax_w[0] * (1.0f / (127.0f * 127.0f));
#pragma unroll
  for (int nj = 0; nj < 4; ++nj) {
    const int col = colBase + wn * 64 + nj * 16 + l15;
    const float bv = bias[col];
#pragma unroll
    for (int mi = 0; mi < 8; ++mi) {
      const int row = rowBase + wm * 128 + mi * 16 + l4 * 4;
#pragma unroll
      for (int r = 0; r < 4; ++r)
        out[(size_t)(row + r) * M + col] = (float)acc[mi][nj][r] * dq + bv;
    }
  }
#undef STAGE
#undef RDA
#undef RDB
#undef MFMAQ
}

// ---------------------------------------------------------------------------
// Launch
// ---------------------------------------------------------------------------
extern "C" void kernel_launch(void* const* d_in, const int* in_sizes, int n_in,
                              void* d_out, int out_size, void* d_ws, size_t ws_size,
                              hipStream_t stream) {
  const float* x      = (const float*)d_in[0];
  const float* w      = (const float*)d_in[1];
  const float* bias   = (const float*)d_in[2];
  const float* amax_x = (const float*)d_in[3];
  const float* amax_w = (const float*)d_in[4];
  float* out = (float*)d_out;

  const int M = in_sizes[2];                    // 4096
  const int K = in_sizes[1] / M;                // 4096
  const int N = (int)((long)in_sizes[0] / K);   // 8192

  signed char* qx = (signed char*)d_ws;         // [N,K] int8
  signed char* qw = qx + (size_t)N * K;         // [M,K] int8

  quant_i8_kernel<<<2048, 256, 0, stream>>>(x, qx, amax_x, N * (K / 4));
  quant_i8_kernel<<<2048, 256, 0, stream>>>(w, qw, amax_w, M * (K / 4));

  const int nwg = (N / 256) * (M / 256);        // 512
  gemm_i8_8p<<<nwg, 512, 0, stream>>>(qx, qw, bias, amax_x, amax_w, out,
                                      N, M, K);
}